// Round 1
// baseline (3541.700 us; speedup 1.0000x reference)
//
#include <hip/hip_runtime.h>
#include <hip/hip_bf16.h>

// Problem constants
#define Lc   2048
#define Dc   512
#define Hc   8
#define DKc  64
#define Bc   2

// ---------------------------------------------------------------------------
// Generic tiled fp32 GEMM: C[M x 512] = A[M x 512] @ W[512 x 512] variants.
// AT: A accessed transposed (A'[m][k] = A[k*M + m])
// WT: W accessed transposed (W'[k][n] = W[n*512 + k])
// SCATTER: write to (B,H,L,DK) layout; else row-major (M,512)
// DUAL: write out2 = acc + bias2 as well (scatter only)
// HASBIAS: out += bias1[col]
// ADDSRC: out += add[row*512+col]
// ---------------------------------------------------------------------------
template<int AT, int WT, int SCATTER, int DUAL, int HASBIAS, int ADDSRC>
__global__ __launch_bounds__(256)
void gemm512(const float* __restrict__ A, const float* __restrict__ W,
             const float* __restrict__ bias1, const float* __restrict__ bias2,
             const float* __restrict__ add,
             float* __restrict__ out1, float* __restrict__ out2, int M)
{
    __shared__ float sA[16][68];
    __shared__ float sW[16][68];
    const int m0 = blockIdx.x * 64;
    const int n0 = blockIdx.y * 64;
    const int t  = threadIdx.x;
    const int tx = t & 15, ty = t >> 4;

    float acc[4][4] = {};

    for (int k0 = 0; k0 < 512; k0 += 16) {
        __syncthreads();
        if (AT) {
            const int mm = t & 63, kb = t >> 6;
#pragma unroll
            for (int p = 0; p < 4; ++p)
                sA[kb + p*4][mm] = A[(size_t)(k0 + kb + p*4) * M + m0 + mm];
        } else {
            const int kkl = t & 15, mb = t >> 4;
#pragma unroll
            for (int p = 0; p < 4; ++p)
                sA[kkl][mb + p*16] = A[(size_t)(m0 + mb + p*16) * 512 + k0 + kkl];
        }
        if (WT) {
            const int kkl = t & 15, nb = t >> 4;
#pragma unroll
            for (int p = 0; p < 4; ++p)
                sW[kkl][nb + p*16] = W[(size_t)(n0 + nb + p*16) * 512 + k0 + kkl];
        } else {
            const int nn = t & 63, kb = t >> 6;
#pragma unroll
            for (int p = 0; p < 4; ++p)
                sW[kb + p*4][nn] = W[(size_t)(k0 + kb + p*4) * 512 + n0 + nn];
        }
        __syncthreads();

#pragma unroll
        for (int kkl = 0; kkl < 16; ++kkl) {
            float4 a4 = *(const float4*)&sA[kkl][ty*4];
            float4 b4 = *(const float4*)&sW[kkl][tx*4];
            float av[4] = {a4.x, a4.y, a4.z, a4.w};
            float bv[4] = {b4.x, b4.y, b4.z, b4.w};
#pragma unroll
            for (int r = 0; r < 4; ++r)
#pragma unroll
                for (int c = 0; c < 4; ++c)
                    acc[r][c] += av[r] * bv[c];
        }
    }

    const int h = n0 >> 6;
#pragma unroll
    for (int r = 0; r < 4; ++r) {
        const int row  = m0 + ty*4 + r;
        const int colb = n0 + tx*4;
        float rv[4];
#pragma unroll
        for (int c = 0; c < 4; ++c) {
            float x = acc[r][c];
            if (HASBIAS) x += bias1[colb + c];
            if (ADDSRC)  x += add[(size_t)row * 512 + colb + c];
            rv[c] = x;
        }
        float4 res = make_float4(rv[0], rv[1], rv[2], rv[3]);
        if (SCATTER) {
            const int bb = row >> 11;        // / L
            const int ii = row & 2047;       // % L
            const size_t idx = (((size_t)(bb*Hc + h)) * Lc + ii) * DKc + tx*4;
            *(float4*)&out1[idx] = res;
            if (DUAL) {
                float4 r2 = make_float4(acc[r][0] + bias2[colb+0],
                                        acc[r][1] + bias2[colb+1],
                                        acc[r][2] + bias2[colb+2],
                                        acc[r][3] + bias2[colb+3]);
                *(float4*)&out2[idx] = r2;
            }
        } else {
            *(float4*)&out1[(size_t)row * 512 + colb] = res;
        }
    }
}

// ---------------------------------------------------------------------------
// Fused relative attention with online softmax.
// One block = one (b, h, 64-query tile). 256 threads, 4 waves.
// Score(i,j) = qc_i . k_j + shiftterm, with d = j-i:
//   d<=0 : qp_i     . QRT[d+L-1]
//   d==1 : 0
//   d>=2 : qp_{i+1} . QRT[d-2]
// Band of <=127 distinct QRT rows per (i-tile, j-tile), indexed by dd=d-dlo.
// ---------------------------------------------------------------------------
__global__ __launch_bounds__(256)
void attn_fused(const float* __restrict__ qc, const float* __restrict__ qp,
                const float* __restrict__ kk, const float* __restrict__ vv,
                const float* __restrict__ QRT, float* __restrict__ Oh)
{
    __shared__ float sQC[64][68];
    __shared__ float sQP[65][68];
    __shared__ float sKT[64][68];     // transposed: [dk][j]
    __shared__ float sV [64][68];     // [j][dk]
    __shared__ float sBand[128][76];  // [dd][dk], pad 76 to spread banks
    __shared__ float sP [64][68];

    const int bx = blockIdx.x;
    const int it = bx & 31;
    const int h  = (bx >> 5) & 7;
    const int b  = bx >> 8;
    const int i0 = it << 6;
    const int t  = threadIdx.x;
    const int tx = t & 15, ty = t >> 4;
    const int tx4 = tx * 4, ty4 = ty * 4;

    const size_t headoff = ((size_t)(b*Hc + h)) * Lc * DKc;
    const float* qcH  = qc + headoff;
    const float* qpH  = qp + headoff;
    const float* kH   = kk + headoff;
    const float* vH   = vv + headoff;
    const float* qrtH = QRT + h * DKc;

    // stage qc/qp tiles (row i0..i0+63, plus qp row i0+64)
    {
        const int c4 = (t & 15) * 4;
        const int rb = t >> 4;
#pragma unroll
        for (int p = 0; p < 4; ++p) {
            const int row = rb + p*16;
            *(float4*)&sQC[row][c4] = *(const float4*)&qcH[(size_t)(i0+row)*DKc + c4];
            *(float4*)&sQP[row][c4] = *(const float4*)&qpH[(size_t)(i0+row)*DKc + c4];
        }
        if (t < 16) {
            const int src = (i0 + 64 < Lc) ? (i0 + 64) : (Lc - 1); // dummy if OOB (never read)
            *(float4*)&sQP[64][t*4] = *(const float4*)&qpH[(size_t)src*DKc + t*4];
        }
    }

    float o[4][4] = {};
    float mrow[4] = {-1e30f, -1e30f, -1e30f, -1e30f};
    float lrow[4] = {};

    for (int jt = 0; jt < 32; ++jt) {
        const int j0 = jt << 6;
        __syncthreads();
        // ---- stage K (transposed), V, band ----
        {
            const int c4 = (t & 15) * 4;
            const int rb = t >> 4;
#pragma unroll
            for (int p = 0; p < 4; ++p) {
                const int row = rb + p*16;
                float4 kv = *(const float4*)&kH[(size_t)(j0+row)*DKc + c4];
                sKT[c4+0][row] = kv.x; sKT[c4+1][row] = kv.y;
                sKT[c4+2][row] = kv.z; sKT[c4+3][row] = kv.w;
                *(float4*)&sV[row][c4] = *(const float4*)&vH[(size_t)(j0+row)*DKc + c4];
            }
            const int dlo = j0 - i0 - 63;
#pragma unroll
            for (int p = 0; p < 8; ++p) {
                const int dd = rb + p*16;
                const int d  = dlo + dd;
                int m = (d <= 0) ? (d + Lc - 1) : (d - 2);
                if (d == 1) m = 0;   // dummy row, value never used
                *(float4*)&sBand[dd][c4] = *(const float4*)&qrtH[(size_t)m * Dc + c4];
            }
        }
        __syncthreads();

        // ---- scores: part 1 (qc . k) ----
        float s[4][4] = {};
#pragma unroll
        for (int k4 = 0; k4 < 64; k4 += 4) {
            float4 a0 = *(const float4*)&sQC[ty4+0][k4];
            float4 a1 = *(const float4*)&sQC[ty4+1][k4];
            float4 a2 = *(const float4*)&sQC[ty4+2][k4];
            float4 a3 = *(const float4*)&sQC[ty4+3][k4];
            float av[4][4] = {{a0.x,a0.y,a0.z,a0.w},{a1.x,a1.y,a1.z,a1.w},
                              {a2.x,a2.y,a2.z,a2.w},{a3.x,a3.y,a3.z,a3.w}};
#pragma unroll
            for (int e = 0; e < 4; ++e) {
                float4 b4 = *(const float4*)&sKT[k4+e][tx4];
                float bv[4] = {b4.x, b4.y, b4.z, b4.w};
#pragma unroll
                for (int r = 0; r < 4; ++r)
#pragma unroll
                    for (int c = 0; c < 4; ++c)
                        s[r][c] += av[r][e] * bv[c];
            }
        }

        // ---- scores: part 2 (shift term) ----
#pragma unroll
        for (int r = 0; r < 4; ++r) {
            const int il = ty4 + r;
#pragma unroll
            for (int c = 0; c < 4; ++c) {
                const int jl = tx4 + c;
                const int d  = (j0 + jl) - (i0 + il);
                if (d != 1) {
                    const int dd = jl - il + 63;
                    const float* qrow = (d <= 0) ? &sQP[il][0] : &sQP[il+1][0];
                    const float* brow = &sBand[dd][0];
                    float acc2 = 0.f;
#pragma unroll 4
                    for (int k4 = 0; k4 < 64; k4 += 4) {
                        float4 qa = *(const float4*)&qrow[k4];
                        float4 ba = *(const float4*)&brow[k4];
                        acc2 += qa.x*ba.x + qa.y*ba.y + qa.z*ba.z + qa.w*ba.w;
                    }
                    s[r][c] += acc2;
                }
            }
        }

        // ---- online softmax (row = ty4+r, 16 tx lanes share a row) ----
#pragma unroll
        for (int r = 0; r < 4; ++r) {
            float mx = fmaxf(fmaxf(s[r][0], s[r][1]), fmaxf(s[r][2], s[r][3]));
#pragma unroll
            for (int off = 1; off < 16; off <<= 1)
                mx = fmaxf(mx, __shfl_xor(mx, off, 64));
            const float mnew = fmaxf(mrow[r], mx);
            float p0 = __expf(s[r][0] - mnew);
            float p1 = __expf(s[r][1] - mnew);
            float p2 = __expf(s[r][2] - mnew);
            float p3 = __expf(s[r][3] - mnew);
            float psum = p0 + p1 + p2 + p3;
#pragma unroll
            for (int off = 1; off < 16; off <<= 1)
                psum += __shfl_xor(psum, off, 64);
            const float f = __expf(mrow[r] - mnew);
            lrow[r] = lrow[r] * f + psum;
            mrow[r] = mnew;
            o[r][0] *= f; o[r][1] *= f; o[r][2] *= f; o[r][3] *= f;
            *(float4*)&sP[ty4+r][tx4] = make_float4(p0, p1, p2, p3);
        }
        __syncthreads();

        // ---- PV accumulate: o[r][dk=tx4+c] += p[i][j] * v[j][dk] ----
#pragma unroll 8
        for (int j = 0; j < 64; ++j) {
            float4 v4 = *(const float4*)&sV[j][tx4];
#pragma unroll
            for (int r = 0; r < 4; ++r) {
                const float pv = sP[ty4+r][j];
                o[r][0] += pv * v4.x; o[r][1] += pv * v4.y;
                o[r][2] += pv * v4.z; o[r][3] += pv * v4.w;
            }
        }
    }

    // ---- epilogue: normalize and store ----
#pragma unroll
    for (int r = 0; r < 4; ++r) {
        const float inv = 1.f / lrow[r];
        *(float4*)&Oh[headoff + (size_t)(i0 + ty4 + r) * DKc + tx4] =
            make_float4(o[r][0]*inv, o[r][1]*inv, o[r][2]*inv, o[r][3]*inv);
    }
}

// ---------------------------------------------------------------------------
// LayerNorm over D=512 per row (4096 rows). 256 threads, 2 elems each.
// ---------------------------------------------------------------------------
__global__ __launch_bounds__(256)
void ln_kernel(const float* __restrict__ yr, const float* __restrict__ g,
               const float* __restrict__ be, float* __restrict__ out)
{
    const int row = blockIdx.x;
    const int t   = threadIdx.x;
    const float2 v = *(const float2*)&yr[(size_t)row * 512 + t*2];
    float sum = v.x + v.y;
    float sq  = v.x*v.x + v.y*v.y;
#pragma unroll
    for (int off = 1; off < 64; off <<= 1) {
        sum += __shfl_xor(sum, off, 64);
        sq  += __shfl_xor(sq,  off, 64);
    }
    __shared__ float ssum[4], ssq[4];
    if ((t & 63) == 0) { ssum[t >> 6] = sum; ssq[t >> 6] = sq; }
    __syncthreads();
    sum = ssum[0] + ssum[1] + ssum[2] + ssum[3];
    sq  = ssq[0]  + ssq[1]  + ssq[2]  + ssq[3];
    const float mu   = sum * (1.f / 512.f);
    const float var  = sq * (1.f / 512.f) - mu * mu;
    const float rstd = rsqrtf(var + 1e-5f);
    float2 ov;
    ov.x = (v.x - mu) * rstd * g[t*2+0] + be[t*2+0];
    ov.y = (v.y - mu) * rstd * g[t*2+1] + be[t*2+1];
    *(float2*)&out[(size_t)row * 512 + t*2] = ov;
}

// ---------------------------------------------------------------------------
extern "C" void kernel_launch(void* const* d_in, const int* in_sizes, int n_in,
                              void* d_out, int out_size, void* d_ws, size_t ws_size,
                              hipStream_t stream)
{
    const float* E    = (const float*)d_in[0];
    const float* Ev   = (const float*)d_in[1];
    const float* R    = (const float*)d_in[2];
    const float* Wq   = (const float*)d_in[3];
    const float* Wke  = (const float*)d_in[4];
    const float* Wv   = (const float*)d_in[5];
    const float* Wkr  = (const float*)d_in[6];
    const float* cb   = (const float*)d_in[7];
    const float* pb   = (const float*)d_in[8];
    const float* Wo_w = (const float*)d_in[9];
    const float* Wo_b = (const float*)d_in[10];
    const float* ln_g = (const float*)d_in[11];
    const float* ln_b = (const float*)d_in[12];
    float* out = (float*)d_out;

    // workspace layout (floats)
    const size_t NQ = (size_t)Bc * Hc * Lc * DKc;   // 2,097,152
    if (ws_size < (NQ * 6 + (size_t)Lc * Dc) * sizeof(float)) return;
    float* qc  = (float*)d_ws;
    float* qp  = qc  + NQ;
    float* kkb = qp  + NQ;
    float* vvb = kkb + NQ;
    float* QRT = vvb + NQ;                // (L, D) = 1,048,576 floats
    float* Oh  = QRT + (size_t)Lc * Dc;
    float* yr  = Oh  + NQ;

    dim3 blk(256);
    // qc = E@Wq + cb ; qp = E@Wq + pb   (scatter to B,H,L,DK)
    gemm512<0,0,1,1,1,0><<<dim3(64,8), blk, 0, stream>>>(E,  Wq,  cb, pb, nullptr, qc,  qp,      4096);
    // k = E@Wke ; v = Ev@Wv
    gemm512<0,0,1,0,0,0><<<dim3(64,8), blk, 0, stream>>>(E,  Wke, nullptr, nullptr, nullptr, kkb, nullptr, 4096);
    gemm512<0,0,1,0,0,0><<<dim3(64,8), blk, 0, stream>>>(Ev, Wv,  nullptr, nullptr, nullptr, vvb, nullptr, 4096);
    // QRT[m, d'] = (Wkr @ R)[d', m]  -> A = R (AT), W = Wkr (WT)
    gemm512<1,1,0,0,0,0><<<dim3(32,8), blk, 0, stream>>>(R,  Wkr, nullptr, nullptr, nullptr, QRT, nullptr, 2048);
    // fused attention
    attn_fused<<<dim3(512), blk, 0, stream>>>(qc, qp, kkb, vvb, QRT, Oh);
    // y = Ev + Oh(flat as 4096x512) @ Wo_w^T + Wo_b
    gemm512<0,1,0,0,1,1><<<dim3(64,8), blk, 0, stream>>>(Oh, Wo_w, Wo_b, nullptr, Ev, yr, nullptr, 4096);
    // layernorm
    ln_kernel<<<dim3(4096), blk, 0, stream>>>(yr, ln_g, ln_b, out);
}

// Round 2
// 292.948 us; speedup vs baseline: 12.0899x; 12.0899x over previous
//
#include <hip/hip_runtime.h>
#include <hip/hip_bf16.h>

// Problem constants
#define Lc   2048
#define Dc   512
#define Hc   8
#define DKc  64
#define Bc   2

typedef __attribute__((ext_vector_type(8))) short bf16x8;
typedef __attribute__((ext_vector_type(4))) float f32x4;
typedef __attribute__((ext_vector_type(4))) int   i32x4;

#define MFMA16(a, b, c) __builtin_amdgcn_mfma_f32_16x16x32_bf16((a), (b), (c), 0, 0, 0)

__device__ __forceinline__ unsigned short f2bf(float x) {
    union { float f; unsigned u; } v; v.f = x;
    unsigned r = v.u + 0x7FFFu + ((v.u >> 16) & 1u);   // RNE
    return (unsigned short)(r >> 16);
}

// ---------------------------------------------------------------------------
// Tiled fp32 GEMM: C[M x 512] = A[M x 512] @ W[512 x 512] variants.
// AT / WT: A / W accessed transposed.
// OUTMODE: 0 = fp32 row-major (M,512)
//          1 = bf16 scatter (B,H,L,DK)        (+DUAL: out2 = acc + bias2)
//          2 = bf16 scatter V^T (B,H,DK,L)
//          3 = bf16 QRT [h][m][dk]
// ---------------------------------------------------------------------------
template<int AT, int WT, int OUTMODE, int DUAL, int HASBIAS, int ADDSRC>
__global__ __launch_bounds__(256)
void gemm512(const float* __restrict__ A, const float* __restrict__ W,
             const float* __restrict__ bias1, const float* __restrict__ bias2,
             const float* __restrict__ add,
             void* __restrict__ out1v, void* __restrict__ out2v, int M)
{
    __shared__ float sA[16][68];
    __shared__ float sW[16][68];
    const int m0 = blockIdx.x * 64;
    const int n0 = blockIdx.y * 64;
    const int t  = threadIdx.x;
    const int tx = t & 15, ty = t >> 4;

    float acc[4][4] = {};

    for (int k0 = 0; k0 < 512; k0 += 16) {
        __syncthreads();
        if (AT) {
            const int mm = t & 63, kb = t >> 6;
#pragma unroll
            for (int p = 0; p < 4; ++p)
                sA[kb + p*4][mm] = A[(size_t)(k0 + kb + p*4) * M + m0 + mm];
        } else {
            const int kkl = t & 15, mb = t >> 4;
#pragma unroll
            for (int p = 0; p < 4; ++p)
                sA[kkl][mb + p*16] = A[(size_t)(m0 + mb + p*16) * 512 + k0 + kkl];
        }
        if (WT) {
            const int kkl = t & 15, nb = t >> 4;
#pragma unroll
            for (int p = 0; p < 4; ++p)
                sW[kkl][nb + p*16] = W[(size_t)(n0 + nb + p*16) * 512 + k0 + kkl];
        } else {
            const int nn = t & 63, kb = t >> 6;
#pragma unroll
            for (int p = 0; p < 4; ++p)
                sW[kb + p*4][nn] = W[(size_t)(k0 + kb + p*4) * 512 + n0 + nn];
        }
        __syncthreads();

#pragma unroll
        for (int kkl = 0; kkl < 16; ++kkl) {
            float4 a4 = *(const float4*)&sA[kkl][ty*4];
            float4 b4 = *(const float4*)&sW[kkl][tx*4];
            float av[4] = {a4.x, a4.y, a4.z, a4.w};
            float bv[4] = {b4.x, b4.y, b4.z, b4.w};
#pragma unroll
            for (int r = 0; r < 4; ++r)
#pragma unroll
                for (int c = 0; c < 4; ++c)
                    acc[r][c] += av[r] * bv[c];
        }
    }

    const int hh = n0 >> 6;
#pragma unroll
    for (int r = 0; r < 4; ++r) {
        const int row  = m0 + ty*4 + r;
        const int colb = n0 + tx*4;
        float rv[4];
#pragma unroll
        for (int c = 0; c < 4; ++c) {
            float x = acc[r][c];
            if (HASBIAS) x += bias1[colb + c];
            if (ADDSRC)  x += add[(size_t)row * 512 + colb + c];
            rv[c] = x;
        }
        if (OUTMODE == 0) {
            float* o1 = (float*)out1v;
            *(float4*)&o1[(size_t)row * 512 + colb] = make_float4(rv[0], rv[1], rv[2], rv[3]);
        } else if (OUTMODE == 1) {
            unsigned short* o1 = (unsigned short*)out1v;
            const int bb = row >> 11, ii = row & 2047;
            const size_t idx = (((size_t)(bb*Hc + hh)) * Lc + ii) * DKc + (colb & 63);
            ushort4 u;
            u.x = f2bf(rv[0]); u.y = f2bf(rv[1]); u.z = f2bf(rv[2]); u.w = f2bf(rv[3]);
            *(ushort4*)&o1[idx] = u;
            if (DUAL) {
                unsigned short* o2 = (unsigned short*)out2v;
                ushort4 u2;
                u2.x = f2bf(acc[r][0] + bias2[colb+0]);
                u2.y = f2bf(acc[r][1] + bias2[colb+1]);
                u2.z = f2bf(acc[r][2] + bias2[colb+2]);
                u2.w = f2bf(acc[r][3] + bias2[colb+3]);
                *(ushort4*)&o2[idx] = u2;
            }
        } else if (OUTMODE == 2) {
            unsigned short* o1 = (unsigned short*)out1v;
            const int bb = row >> 11, ii = row & 2047;
            const int dkb = colb & 63;
#pragma unroll
            for (int c = 0; c < 4; ++c)
                o1[(((size_t)(bb*Hc + hh)) * DKc + dkb + c) * Lc + ii] = f2bf(rv[c]);
        } else {
            unsigned short* o1 = (unsigned short*)out1v;
            const size_t idx = ((size_t)hh * Lc + row) * DKc + (colb & 63);
            ushort4 u;
            u.x = f2bf(rv[0]); u.y = f2bf(rv[1]); u.z = f2bf(rv[2]); u.w = f2bf(rv[3]);
            *(ushort4*)&o1[idx] = u;
        }
    }
}

// ---------------------------------------------------------------------------
// MFMA fused relative attention, bf16 inputs, online softmax.
// One block = one (b, h, 64-query tile). 256 threads = 4 waves; wave w owns
// score/output rows [16w, 16w+16). Per j-tile:
//   S  = qc @ K^T                    (MFMA, K from sK   [j][dk] swizzled)
//   P2 = qpX @ Band^T  (X per 16-col block: qp_{i+1} iff dBase+16cb >= 1)
//   S += gather P2[bl][jl-bl+63]     (0 where d==1)
//   online softmax; P -> bf16 -> sP; O += P @ V  (V from sVT [dk][j])
// All bf16 LDS tiles: row stride 64, 16B-group XOR swizzle g^=(row&7).
// ---------------------------------------------------------------------------
__global__ __launch_bounds__(256)
void attn_mfma(const unsigned short* __restrict__ qc, const unsigned short* __restrict__ qp,
               const unsigned short* __restrict__ kk, const unsigned short* __restrict__ vt,
               const unsigned short* __restrict__ qrt, float* __restrict__ Oh)
{
    __shared__ __align__(16) unsigned short sK[64*64];
    __shared__ __align__(16) unsigned short sVT[64*64];
    __shared__ __align__(16) unsigned short sBand[128*64];
    __shared__ __align__(16) float sP2[64*132];
    __shared__ __align__(16) unsigned short sP[64*64];

    const int bx = blockIdx.x;
    const int it = bx & 31, h = (bx >> 5) & 7, b = bx >> 8;
    const int i0 = it << 6;
    const int t = threadIdx.x;
    const int lane = t & 63, w = t >> 6;
    const int l15 = lane & 15, lg = lane >> 4;

    const size_t ho = (size_t)(b*Hc + h) * (Lc * DKc);
    const unsigned short* qcH  = qc  + ho;
    const unsigned short* qpH  = qp  + ho;
    const unsigned short* kH   = kk  + ho;
    const unsigned short* vtH  = vt  + ho;
    const unsigned short* qrtH = qrt + (size_t)h * (Lc * DKc);

    // Q fragments in registers (A-operands: row = l15, k-group = lg)
    const int rowA = i0 + w*16 + l15;
    const int rowB = (rowA + 1 < Lc) ? rowA + 1 : Lc - 1;  // clamp: clamped rows never gathered
    bf16x8 qc0 = *(const bf16x8*)(qcH + (size_t)rowA*64 +      lg*8);
    bf16x8 qc1 = *(const bf16x8*)(qcH + (size_t)rowA*64 + 32 + lg*8);
    bf16x8 qa0 = *(const bf16x8*)(qpH + (size_t)rowA*64 +      lg*8);
    bf16x8 qa1 = *(const bf16x8*)(qpH + (size_t)rowA*64 + 32 + lg*8);
    bf16x8 qb0 = *(const bf16x8*)(qpH + (size_t)rowB*64 +      lg*8);
    bf16x8 qb1 = *(const bf16x8*)(qpH + (size_t)rowB*64 + 32 + lg*8);

    f32x4 oacc[4] = {};
    float mrow[4] = {-1e30f, -1e30f, -1e30f, -1e30f};
    float lrow[4] = {0.f, 0.f, 0.f, 0.f};

    for (int jt = 0; jt < 32; ++jt) {
        const int j0 = jt << 6;
        const int dBase = j0 - i0 - 63;
        __syncthreads();
        // ---- stage K, VT (512 16B-slots each), Band (1024 slots) ----
#pragma unroll
        for (int p = 0; p < 2; ++p) {
            const int s = t + p*256;
            const int row = s >> 3, g = s & 7;
            const int sl = row*64 + ((g ^ (row & 7)) << 3);
            *(i32x4*)&sK[sl]  = *(const i32x4*)(kH  + (size_t)(j0+row)*64 + g*8);
            *(i32x4*)&sVT[sl] = *(const i32x4*)(vtH + (size_t)row*Lc + j0 + g*8);
        }
#pragma unroll
        for (int p = 0; p < 4; ++p) {
            const int s = t + p*256;
            const int dd = s >> 3, g = s & 7;
            const int d = dBase + dd;
            const int m = (d <= 0) ? (d + Lc - 1) : ((d >= 2) ? (d - 2) : 0);
            *(i32x4*)&sBand[dd*64 + ((g ^ (dd & 7)) << 3)] =
                *(const i32x4*)(qrtH + (size_t)m*64 + g*8);
        }
        __syncthreads();

        // ---- qk scores ----
        f32x4 sc[4];
#pragma unroll
        for (int nb = 0; nb < 4; ++nb) {
            const int row = nb*16 + l15;
            bf16x8 k0 = *(const bf16x8*)&sK[row*64 + ((( lg    ) ^ (row & 7)) << 3)];
            bf16x8 k1 = *(const bf16x8*)&sK[row*64 + (((lg + 4) ^ (row & 7)) << 3)];
            f32x4 z = {0.f, 0.f, 0.f, 0.f};
            z = MFMA16(qc0, k0, z);
            z = MFMA16(qc1, k1, z);
            sc[nb] = z;
        }

        // ---- P2 band GEMM (per-wave strip rows), write to sP2 ----
#pragma unroll
        for (int cb = 0; cb < 8; ++cb) {
            const int row = cb*16 + l15;
            bf16x8 b0 = *(const bf16x8*)&sBand[row*64 + ((( lg    ) ^ (row & 7)) << 3)];
            bf16x8 b1 = *(const bf16x8*)&sBand[row*64 + (((lg + 4) ^ (row & 7)) << 3)];
            f32x4 z = {0.f, 0.f, 0.f, 0.f};
            if ((dBase + cb*16) >= 1) {
                z = MFMA16(qb0, b0, z);
                z = MFMA16(qb1, b1, z);
            } else {
                z = MFMA16(qa0, b0, z);
                z = MFMA16(qa1, b1, z);
            }
#pragma unroll
            for (int r = 0; r < 4; ++r)
                sP2[(w*16 + lg*4 + r)*132 + cb*16 + l15] = z[r];
        }
        __asm__ volatile("" ::: "memory");   // keep gather after P2 writes

        // ---- gather shift term + online softmax ----
        const int blr0 = w*16 + lg*4;
        float fsc[4];
#pragma unroll
        for (int r = 0; r < 4; ++r) {
            const int bl = blr0 + r;
#pragma unroll
            for (int nb = 0; nb < 4; ++nb) {
                const int jl = nb*16 + l15;
                const int dd = jl - bl + 63;
                const int d  = dBase + dd;
                sc[nb][r] += (d == 1) ? 0.f : sP2[bl*132 + dd];
            }
            float mx = fmaxf(fmaxf(sc[0][r], sc[1][r]), fmaxf(sc[2][r], sc[3][r]));
            mx = fmaxf(mx, __shfl_xor(mx, 1, 64));
            mx = fmaxf(mx, __shfl_xor(mx, 2, 64));
            mx = fmaxf(mx, __shfl_xor(mx, 4, 64));
            mx = fmaxf(mx, __shfl_xor(mx, 8, 64));
            const float mnew = fmaxf(mrow[r], mx);
            const float fac  = __expf(mrow[r] - mnew);
            mrow[r] = mnew;
            float p0 = __expf(sc[0][r] - mnew);
            float p1 = __expf(sc[1][r] - mnew);
            float p2 = __expf(sc[2][r] - mnew);
            float p3 = __expf(sc[3][r] - mnew);
            sc[0][r] = p0; sc[1][r] = p1; sc[2][r] = p2; sc[3][r] = p3;
            float ps = p0 + p1 + p2 + p3;
            ps += __shfl_xor(ps, 1, 64);
            ps += __shfl_xor(ps, 2, 64);
            ps += __shfl_xor(ps, 4, 64);
            ps += __shfl_xor(ps, 8, 64);
            lrow[r] = lrow[r] * fac + ps;
            fsc[r] = fac;
        }
#pragma unroll
        for (int nb = 0; nb < 4; ++nb)
#pragma unroll
            for (int r = 0; r < 4; ++r)
                oacc[nb][r] *= fsc[r];

        // ---- write P (bf16, swizzled) ----
#pragma unroll
        for (int r = 0; r < 4; ++r) {
            const int bl = blr0 + r;
#pragma unroll
            for (int nb = 0; nb < 4; ++nb) {
                const int jl = nb*16 + l15;
                sP[bl*64 + (((jl >> 3) ^ (bl & 7)) << 3) + (jl & 7)] = f2bf(sc[nb][r]);
            }
        }
        __asm__ volatile("" ::: "memory");   // keep PV reads after P writes

        // ---- PV ----
        {
            const int prow = w*16 + l15;
            bf16x8 pa0 = *(const bf16x8*)&sP[prow*64 + ((( lg    ) ^ (prow & 7)) << 3)];
            bf16x8 pa1 = *(const bf16x8*)&sP[prow*64 + (((lg + 4) ^ (prow & 7)) << 3)];
#pragma unroll
            for (int nb = 0; nb < 4; ++nb) {
                const int row = nb*16 + l15;
                bf16x8 v0 = *(const bf16x8*)&sVT[row*64 + ((( lg    ) ^ (row & 7)) << 3)];
                bf16x8 v1 = *(const bf16x8*)&sVT[row*64 + (((lg + 4) ^ (row & 7)) << 3)];
                oacc[nb] = MFMA16(pa0, v0, oacc[nb]);
                oacc[nb] = MFMA16(pa1, v1, oacc[nb]);
            }
        }
    }

    // ---- epilogue: normalize, store Oh (B,H,L,DK) fp32 ----
#pragma unroll
    for (int r = 0; r < 4; ++r) {
        const int bl  = w*16 + lg*4 + r;
        const float inv = 1.f / lrow[r];
#pragma unroll
        for (int nb = 0; nb < 4; ++nb)
            Oh[ho + (size_t)(i0 + bl)*64 + nb*16 + l15] = oacc[nb][r] * inv;
    }
}

// ---------------------------------------------------------------------------
// LayerNorm over D=512 per row (4096 rows).
// ---------------------------------------------------------------------------
__global__ __launch_bounds__(256)
void ln_kernel(const float* __restrict__ yr, const float* __restrict__ g,
               const float* __restrict__ be, float* __restrict__ out)
{
    const int row = blockIdx.x;
    const int t   = threadIdx.x;
    const float2 v = *(const float2*)&yr[(size_t)row * 512 + t*2];
    float sum = v.x + v.y;
    float sq  = v.x*v.x + v.y*v.y;
#pragma unroll
    for (int off = 1; off < 64; off <<= 1) {
        sum += __shfl_xor(sum, off, 64);
        sq  += __shfl_xor(sq,  off, 64);
    }
    __shared__ float ssum[4], ssq[4];
    if ((t & 63) == 0) { ssum[t >> 6] = sum; ssq[t >> 6] = sq; }
    __syncthreads();
    sum = ssum[0] + ssum[1] + ssum[2] + ssum[3];
    sq  = ssq[0]  + ssq[1]  + ssq[2]  + ssq[3];
    const float mu   = sum * (1.f / 512.f);
    const float var  = sq * (1.f / 512.f) - mu * mu;
    const float rstd = rsqrtf(var + 1e-5f);
    float2 ov;
    ov.x = (v.x - mu) * rstd * g[t*2+0] + be[t*2+0];
    ov.y = (v.y - mu) * rstd * g[t*2+1] + be[t*2+1];
    *(float2*)&out[(size_t)row * 512 + t*2] = ov;
}

// ---------------------------------------------------------------------------
extern "C" void kernel_launch(void* const* d_in, const int* in_sizes, int n_in,
                              void* d_out, int out_size, void* d_ws, size_t ws_size,
                              hipStream_t stream)
{
    const float* E    = (const float*)d_in[0];
    const float* Ev   = (const float*)d_in[1];
    const float* R    = (const float*)d_in[2];
    const float* Wq   = (const float*)d_in[3];
    const float* Wke  = (const float*)d_in[4];
    const float* Wv   = (const float*)d_in[5];
    const float* Wkr  = (const float*)d_in[6];
    const float* cb   = (const float*)d_in[7];
    const float* pb   = (const float*)d_in[8];
    const float* Wo_w = (const float*)d_in[9];
    const float* Wo_b = (const float*)d_in[10];
    const float* ln_g = (const float*)d_in[11];
    const float* ln_b = (const float*)d_in[12];
    float* out = (float*)d_out;

    const size_t NQ = (size_t)Bc * Hc * Lc * DKc;   // 2,097,152
    const size_t NR = (size_t)Hc * Lc * DKc;        // 1,048,576
    const size_t need = NQ*2*4 + NR*2 + NQ*4*2;     // ~34 MB
    if (ws_size < need) return;

    unsigned short* qcB  = (unsigned short*)d_ws;
    unsigned short* qpB  = qcB + NQ;
    unsigned short* kB   = qpB + NQ;
    unsigned short* vtB  = kB  + NQ;
    unsigned short* qrtB = vtB + NQ;
    float* Oh = (float*)(qrtB + NR);
    float* yr = Oh + NQ;

    dim3 blk(256);
    // qc = E@Wq + cb ; qp = E@Wq + pb   (bf16 scatter B,H,L,DK)
    gemm512<0,0,1,1,1,0><<<dim3(64,8), blk, 0, stream>>>(E,  Wq,  cb, pb, nullptr, qcB, qpB, 4096);
    // k = E@Wke (bf16 B,H,L,DK)
    gemm512<0,0,1,0,0,0><<<dim3(64,8), blk, 0, stream>>>(E,  Wke, nullptr, nullptr, nullptr, kB,  nullptr, 4096);
    // v = Ev@Wv (bf16 V^T: B,H,DK,L)
    gemm512<0,0,2,0,0,0><<<dim3(64,8), blk, 0, stream>>>(Ev, Wv,  nullptr, nullptr, nullptr, vtB, nullptr, 4096);
    // QRT[h][m][dk] = (Wkr@R)[h*64+dk][m]  (bf16)
    gemm512<1,1,3,0,0,0><<<dim3(32,8), blk, 0, stream>>>(R,  Wkr, nullptr, nullptr, nullptr, qrtB, nullptr, 2048);
    // fused MFMA attention
    attn_mfma<<<dim3(512), blk, 0, stream>>>(qcB, qpB, kB, vtB, qrtB, Oh);
    // y = Ev + Oh(flat 4096x512) @ Wo_w^T + Wo_b (fp32)
    gemm512<0,1,0,0,1,1><<<dim3(64,8), blk, 0, stream>>>(Oh, Wo_w, Wo_b, nullptr, Ev, yr, nullptr, 4096);
    // layernorm
    ln_kernel<<<dim3(4096), blk, 0, stream>>>(yr, ln_g, ln_b, out);
}

// Round 4
// 277.324 us; speedup vs baseline: 12.7710x; 1.0563x over previous
//
#include <hip/hip_runtime.h>
#include <hip/hip_bf16.h>

// Problem constants
#define Lc   2048
#define Dc   512
#define Hc   8
#define DKc  64
#define Bc   2

typedef __attribute__((ext_vector_type(8))) short bf16x8;
typedef __attribute__((ext_vector_type(4))) float f32x4;
typedef __attribute__((ext_vector_type(4))) int   i32x4;
typedef unsigned short u16;

#define MFMA16(a, b, c) __builtin_amdgcn_mfma_f32_16x16x32_bf16((a), (b), (c), 0, 0, 0)

__device__ __forceinline__ u16 f2bf(float x) {
    union { float f; unsigned u; } v; v.f = x;
    unsigned r = v.u + 0x7FFFu + ((v.u >> 16) & 1u);   // RNE
    return (u16)(r >> 16);
}

union U16x8 { u16 us[8]; i32x4 v; };

// ---------------------------------------------------------------------------
// Stage a 64x64 fp32 tile -> bf16 LDS [row][k], XOR-swizzled 16B groups
// (slot g ^= row&7). TRANS=0: sDst[row][k] = src[(r0+row)*ld + k0+k]
//                    TRANS=1: sDst[row][k] = src[(k0+k)*ld + r0+row]
// ---------------------------------------------------------------------------
template<int TRANS>
__device__ __forceinline__ void stage_tile(u16* sDst, const float* __restrict__ src,
                                           int r0, int k0, int ld, int t)
{
    if (!TRANS) {
        const int row = t >> 2, q = t & 3;
        const float* s = src + (size_t)(r0 + row) * ld + k0 + q * 16;
        float4 f0 = ((const float4*)s)[0];
        float4 f1 = ((const float4*)s)[1];
        float4 f2 = ((const float4*)s)[2];
        float4 f3 = ((const float4*)s)[3];
        U16x8 a, b;
        a.us[0]=f2bf(f0.x); a.us[1]=f2bf(f0.y); a.us[2]=f2bf(f0.z); a.us[3]=f2bf(f0.w);
        a.us[4]=f2bf(f1.x); a.us[5]=f2bf(f1.y); a.us[6]=f2bf(f1.z); a.us[7]=f2bf(f1.w);
        b.us[0]=f2bf(f2.x); b.us[1]=f2bf(f2.y); b.us[2]=f2bf(f2.z); b.us[3]=f2bf(f2.w);
        b.us[4]=f2bf(f3.x); b.us[5]=f2bf(f3.y); b.us[6]=f2bf(f3.z); b.us[7]=f2bf(f3.w);
        const int r7 = row & 7, base = row * 64;
        *(i32x4*)&sDst[base + (((q*2)     ^ r7) << 3)] = a.v;
        *(i32x4*)&sDst[base + (((q*2 + 1) ^ r7) << 3)] = b.v;
    } else {
        const int qq = t & 31, mg = t >> 5;      // k-pair 2*qq, row-chunk mg*8
        const float* s0 = src + (size_t)(k0 + 2*qq) * ld + r0 + mg*8;
        const float* s1 = s0 + ld;
        float4 x0 = ((const float4*)s0)[0], x1 = ((const float4*)s0)[1];
        float4 y0 = ((const float4*)s1)[0], y1 = ((const float4*)s1)[1];
        float e0[8] = {x0.x,x0.y,x0.z,x0.w,x1.x,x1.y,x1.z,x1.w};
        float e1[8] = {y0.x,y0.y,y0.z,y0.w,y1.x,y1.y,y1.z,y1.w};
        unsigned* d32 = (unsigned*)sDst;
        const int g = qq >> 2, off = qq & 3;
#pragma unroll
        for (int e = 0; e < 8; ++e) {
            const int m = mg*8 + e;
            unsigned pk = (unsigned)f2bf(e0[e]) | ((unsigned)f2bf(e1[e]) << 16);
            d32[m*32 + ((g ^ (m & 7)) << 2) + off] = pk;
        }
    }
}

// ---------------------------------------------------------------------------
// MFMA GEMM: C[M x N] = A'[M x 512] @ W'[512 x N], bf16 inputs (converted in
// staging), f32 accum. 64x64 block tile, 4 waves (2x2), wave tile 32x32.
// AT: A'[m][k] = A[k*ldA + m]        (else A[m*512+k])
// WT: W'[k][n] = W[n*512 + k]        (else W[k*512+n])   [sB wants [n][k]!]
// OUTMODE: 0 fp32 row-major (+bias/add), 1 bf16 scatter (B,H,L,DK) (+DUAL),
//          2 bf16 scatter V^T (B,H,DK,L)  (rows are d', cols are ii),
//          3 bf16 QRT [h][m][dk]
// ---------------------------------------------------------------------------
template<int AT, int WT, int OUTMODE, int DUAL, int HASBIAS, int ADDSRC>
__global__ __launch_bounds__(256)
void gemm_mfma(const float* __restrict__ A, const float* __restrict__ W,
               const float* __restrict__ b1, const float* __restrict__ b2,
               const float* __restrict__ add, void* __restrict__ o1v,
               void* __restrict__ o2v, int ldA)
{
    __shared__ __align__(16) u16 sA[64*64];
    __shared__ __align__(16) u16 sB[64*64];
    const int m0 = blockIdx.x * 64, n0 = blockIdx.y * 64;
    const int t = threadIdx.x, lane = t & 63, w = t >> 6;
    const int l15 = lane & 15, lg = lane >> 4;
    const int wm = w >> 1, wn = w & 1;

    f32x4 acc[2][2] = {};

    for (int k0 = 0; k0 < 512; k0 += 64) {
        __syncthreads();
        stage_tile<AT>(sA, A, m0, k0, AT ? ldA : 512, t);
        stage_tile<WT ? 0 : 1>(sB, W, n0, k0, 512, t);
        __syncthreads();
        const int l7 = l15 & 7;
#pragma unroll
        for (int kh = 0; kh < 2; ++kh) {
            bf16x8 av[2], bv[2];
#pragma unroll
            for (int f = 0; f < 2; ++f) {
                const int ra = wm*32 + f*16 + l15;
                av[f] = *(const bf16x8*)&sA[ra*64 + (((kh*4 + lg) ^ l7) << 3)];
                const int rb = wn*32 + f*16 + l15;
                bv[f] = *(const bf16x8*)&sB[rb*64 + (((kh*4 + lg) ^ l7) << 3)];
            }
#pragma unroll
            for (int fm = 0; fm < 2; ++fm)
#pragma unroll
                for (int fn = 0; fn < 2; ++fn)
                    acc[fm][fn] = MFMA16(av[fm], bv[fn], acc[fm][fn]);
        }
    }

#pragma unroll
    for (int fm = 0; fm < 2; ++fm)
#pragma unroll
    for (int fn = 0; fn < 2; ++fn) {
        const int colg = n0 + wn*32 + fn*16 + l15;
#pragma unroll
        for (int r = 0; r < 4; ++r) {
            const int row = m0 + wm*32 + fm*16 + lg*4 + r;
            float v = acc[fm][fn][r];
            if (OUTMODE == 0) {
                if (HASBIAS) v += b1[colg];
                if (ADDSRC)  v += add[(size_t)row*512 + colg];
                ((float*)o1v)[(size_t)row*512 + colg] = v;
            } else if (OUTMODE == 1) {
                if (HASBIAS) v += b1[colg];
                const int h = colg >> 6, dk = colg & 63;
                const int bb = row >> 11, ii = row & 2047;
                const size_t idx = (((size_t)(bb*Hc + h)*Lc + ii) << 6) + dk;
                ((u16*)o1v)[idx] = f2bf(v);
                if (DUAL)
                    ((u16*)o2v)[idx] = f2bf(acc[fm][fn][r] + b2[colg]);
            } else if (OUTMODE == 2) {
                const int h = row >> 6, dk = row & 63;
                const int bb = colg >> 11, ii = colg & 2047;
                ((u16*)o1v)[((size_t)(bb*Hc + h)*DKc + dk)*Lc + ii] = f2bf(v);
            } else {
                const int h = colg >> 6, dk = colg & 63;
                ((u16*)o1v)[(((size_t)h*Lc + row) << 6) + dk] = f2bf(v);
            }
        }
    }
}

// ---------------------------------------------------------------------------
// MFMA fused relative attention (see round-2 header for the math).
// Round-3: T14 async staging (issue next-tile loads before compute, write
// LDS after barrier), compact P2 (slot c == jl), per-wave sP2/sP union,
// s_setprio around MFMA clusters. LDS: 8+8+16+18 = 50 KB.
// ---------------------------------------------------------------------------
__global__ __launch_bounds__(256)
void attn_mfma(const u16* __restrict__ qc, const u16* __restrict__ qp,
               const u16* __restrict__ kk, const u16* __restrict__ vt,
               const u16* __restrict__ qrt, float* __restrict__ Oh)
{
    __shared__ __align__(16) u16 sK[64*64];
    __shared__ __align__(16) u16 sVT[64*64];
    __shared__ __align__(16) u16 sBand[128*64];
    __shared__ __align__(16) char sPU[4*4608];   // per-wave: f32[16][68] P2  U  u16[16][64] P

    const int bx = blockIdx.x;
    const int it = bx & 31, h = (bx >> 5) & 7, b = bx >> 8;
    const int i0 = it << 6;
    const int t = threadIdx.x;
    const int lane = t & 63, w = t >> 6;
    const int l15 = lane & 15, lg = lane >> 4;

    float* p2w = (float*)(sPU + (size_t)w * 4608);
    u16*   spw = (u16*)(sPU + (size_t)w * 4608);

    const size_t ho = (size_t)(b*Hc + h) * (Lc * DKc);
    const u16* qcH  = qc  + ho;
    const u16* qpH  = qp  + ho;
    const u16* kH   = kk  + ho;
    const u16* vtH  = vt  + ho;
    const u16* qrtH = qrt + (size_t)h * (Lc * DKc);

    // Q fragments in registers
    const int rowA = i0 + w*16 + l15;
    const int rowB = (rowA + 1 < Lc) ? rowA + 1 : Lc - 1;
    bf16x8 qc0 = *(const bf16x8*)(qcH + (size_t)rowA*64 +      lg*8);
    bf16x8 qc1 = *(const bf16x8*)(qcH + (size_t)rowA*64 + 32 + lg*8);
    bf16x8 qa0 = *(const bf16x8*)(qpH + (size_t)rowA*64 +      lg*8);
    bf16x8 qa1 = *(const bf16x8*)(qpH + (size_t)rowA*64 + 32 + lg*8);
    bf16x8 qb0 = *(const bf16x8*)(qpH + (size_t)rowB*64 +      lg*8);
    bf16x8 qb1 = *(const bf16x8*)(qpH + (size_t)rowB*64 + 32 + lg*8);

    f32x4 oacc[4] = {};
    float mrow[4] = {-1e30f, -1e30f, -1e30f, -1e30f};
    float lrow[4] = {0.f, 0.f, 0.f, 0.f};

    i32x4 rK[2], rV[2], rB[4];

    auto issue_loads = [&](int jt) {
        const int j0n = jt << 6;
        const int dB  = j0n - i0 - 63;
#pragma unroll
        for (int p = 0; p < 2; ++p) {
            const int s = t + p*256, row = s >> 3, g = s & 7;
            rK[p] = *(const i32x4*)(kH  + (size_t)(j0n + row)*64 + g*8);
            rV[p] = *(const i32x4*)(vtH + (size_t)row*Lc + j0n + g*8);
        }
#pragma unroll
        for (int p = 0; p < 4; ++p) {
            const int s = t + p*256, dd = s >> 3, g = s & 7;
            const int d = dB + dd;
            const int m = (d <= 0) ? (d + Lc - 1) : ((d >= 2) ? (d - 2) : 0);
            rB[p] = *(const i32x4*)(qrtH + (size_t)m*64 + g*8);
        }
    };
    auto write_lds = [&]() {
#pragma unroll
        for (int p = 0; p < 2; ++p) {
            const int s = t + p*256, row = s >> 3, g = s & 7;
            const int sl = row*64 + ((g ^ (row & 7)) << 3);
            *(i32x4*)&sK[sl]  = rK[p];
            *(i32x4*)&sVT[sl] = rV[p];
        }
#pragma unroll
        for (int p = 0; p < 4; ++p) {
            const int s = t + p*256, dd = s >> 3, g = s & 7;
            *(i32x4*)&sBand[dd*64 + ((g ^ (dd & 7)) << 3)] = rB[p];
        }
    };

    issue_loads(0);
    write_lds();
    __syncthreads();

    for (int jt = 0; jt < 32; ++jt) {
        const int j0 = jt << 6;
        const int dBase = j0 - i0 - 63;
        if (jt + 1 < 32) issue_loads(jt + 1);

        // ---- qk scores ----
        __builtin_amdgcn_s_setprio(1);
        f32x4 sc[4];
#pragma unroll
        for (int nb = 0; nb < 4; ++nb) {
            const int row = nb*16 + l15;
            bf16x8 k0 = *(const bf16x8*)&sK[row*64 + ((( lg    ) ^ (row & 7)) << 3)];
            bf16x8 k1 = *(const bf16x8*)&sK[row*64 + (((lg + 4) ^ (row & 7)) << 3)];
            f32x4 z = {0.f, 0.f, 0.f, 0.f};
            z = MFMA16(qc0, k0, z);
            z = MFMA16(qc1, k1, z);
            sc[nb] = z;
        }

        // ---- P2 band GEMM -> compact per-wave LDS (slot c == jl) ----
#pragma unroll
        for (int cb = 0; cb < 8; ++cb) {
            const int row = cb*16 + l15;
            bf16x8 b0 = *(const bf16x8*)&sBand[row*64 + ((( lg    ) ^ (row & 7)) << 3)];
            bf16x8 b1 = *(const bf16x8*)&sBand[row*64 + (((lg + 4) ^ (row & 7)) << 3)];
            f32x4 z = {0.f, 0.f, 0.f, 0.f};
            if ((dBase + cb*16) >= 1) {
                z = MFMA16(qb0, b0, z);
                z = MFMA16(qb1, b1, z);
            } else {
                z = MFMA16(qa0, b0, z);
                z = MFMA16(qa1, b1, z);
            }
#pragma unroll
            for (int r = 0; r < 4; ++r) {
                const int blm = lg*4 + r;
                const int c = cb*16 + l15 + (w*16 + blm) - 63;
                if (c >= 0 && c < 64) p2w[blm*68 + c] = z[r];
            }
        }
        __builtin_amdgcn_s_setprio(0);
        __asm__ volatile("" ::: "memory");

        // ---- gather shift term + online softmax ----
        float fsc[4];
#pragma unroll
        for (int r = 0; r < 4; ++r) {
            const int blm = lg*4 + r;
            const int blg = w*16 + blm;
#pragma unroll
            for (int nb = 0; nb < 4; ++nb) {
                const int jl = nb*16 + l15;
                const int d  = dBase + jl - blg + 63;
                const float pv = p2w[blm*68 + jl];
                sc[nb][r] += (d == 1) ? 0.f : pv;
            }
            float mx = fmaxf(fmaxf(sc[0][r], sc[1][r]), fmaxf(sc[2][r], sc[3][r]));
            mx = fmaxf(mx, __shfl_xor(mx, 1, 64));
            mx = fmaxf(mx, __shfl_xor(mx, 2, 64));
            mx = fmaxf(mx, __shfl_xor(mx, 4, 64));
            mx = fmaxf(mx, __shfl_xor(mx, 8, 64));
            const float mnew = fmaxf(mrow[r], mx);
            const float fac  = __expf(mrow[r] - mnew);
            mrow[r] = mnew;
            float p0 = __expf(sc[0][r] - mnew);
            float p1 = __expf(sc[1][r] - mnew);
            float p2 = __expf(sc[2][r] - mnew);
            float p3 = __expf(sc[3][r] - mnew);
            sc[0][r] = p0; sc[1][r] = p1; sc[2][r] = p2; sc[3][r] = p3;
            float ps = p0 + p1 + p2 + p3;
            ps += __shfl_xor(ps, 1, 64);
            ps += __shfl_xor(ps, 2, 64);
            ps += __shfl_xor(ps, 4, 64);
            ps += __shfl_xor(ps, 8, 64);
            lrow[r] = lrow[r] * fac + ps;
            fsc[r] = fac;
        }
#pragma unroll
        for (int nb = 0; nb < 4; ++nb)
#pragma unroll
            for (int r = 0; r < 4; ++r)
                oacc[nb][r] *= fsc[r];
        __asm__ volatile("" ::: "memory");

        // ---- write P (bf16, swizzled, overwrites P2 region; wave-private) ----
#pragma unroll
        for (int r = 0; r < 4; ++r) {
            const int blm = lg*4 + r;
#pragma unroll
            for (int nb = 0; nb < 4; ++nb) {
                const int jl = nb*16 + l15;
                spw[blm*64 + (((jl >> 3) ^ (blm & 7)) << 3) + (jl & 7)] = f2bf(sc[nb][r]);
            }
        }
        __asm__ volatile("" ::: "memory");

        // ---- PV ----
        __builtin_amdgcn_s_setprio(1);
        {
            bf16x8 pa0 = *(const bf16x8*)&spw[l15*64 + ((( lg    ) ^ (l15 & 7)) << 3)];
            bf16x8 pa1 = *(const bf16x8*)&spw[l15*64 + (((lg + 4) ^ (l15 & 7)) << 3)];
#pragma unroll
            for (int nb = 0; nb < 4; ++nb) {
                const int row = nb*16 + l15;
                bf16x8 v0 = *(const bf16x8*)&sVT[row*64 + ((( lg    ) ^ (row & 7)) << 3)];
                bf16x8 v1 = *(const bf16x8*)&sVT[row*64 + (((lg + 4) ^ (row & 7)) << 3)];
                oacc[nb] = MFMA16(pa0, v0, oacc[nb]);
                oacc[nb] = MFMA16(pa1, v1, oacc[nb]);
            }
        }
        __builtin_amdgcn_s_setprio(0);

        __syncthreads();
        if (jt + 1 < 32) write_lds();
        __syncthreads();
    }

    // ---- epilogue: normalize, store Oh (B,H,L,DK) fp32 ----
#pragma unroll
    for (int r = 0; r < 4; ++r) {
        const int bl  = w*16 + lg*4 + r;
        const float inv = 1.f / lrow[r];
#pragma unroll
        for (int nb = 0; nb < 4; ++nb)
            Oh[ho + (size_t)(i0 + bl)*64 + nb*16 + l15] = oacc[nb][r] * inv;
    }
}

// ---------------------------------------------------------------------------
// LayerNorm over D=512 per row (4096 rows).
// ---------------------------------------------------------------------------
__global__ __launch_bounds__(256)
void ln_kernel(const float* __restrict__ yr, const float* __restrict__ g,
               const float* __restrict__ be, float* __restrict__ out)
{
    const int row = blockIdx.x;
    const int t   = threadIdx.x;
    const float2 v = *(const float2*)&yr[(size_t)row * 512 + t*2];
    float sum = v.x + v.y;
    float sq  = v.x*v.x + v.y*v.y;
#pragma unroll
    for (int off = 1; off < 64; off <<= 1) {
        sum += __shfl_xor(sum, off, 64);
        sq  += __shfl_xor(sq,  off, 64);
    }
    __shared__ float ssum[4], ssq[4];
    if ((t & 63) == 0) { ssum[t >> 6] = sum; ssq[t >> 6] = sq; }
    __syncthreads();
    sum = ssum[0] + ssum[1] + ssum[2] + ssum[3];
    sq  = ssq[0]  + ssq[1]  + ssq[2]  + ssq[3];
    const float mu   = sum * (1.f / 512.f);
    const float var  = sq * (1.f / 512.f) - mu * mu;
    const float rstd = rsqrtf(var + 1e-5f);
    float2 ov;
    ov.x = (v.x - mu) * rstd * g[t*2+0] + be[t*2+0];
    ov.y = (v.y - mu) * rstd * g[t*2+1] + be[t*2+1];
    *(float2*)&out[(size_t)row * 512 + t*2] = ov;
}

// ---------------------------------------------------------------------------
extern "C" void kernel_launch(void* const* d_in, const int* in_sizes, int n_in,
                              void* d_out, int out_size, void* d_ws, size_t ws_size,
                              hipStream_t stream)
{
    const float* E    = (const float*)d_in[0];
    const float* Ev   = (const float*)d_in[1];
    const float* R    = (const float*)d_in[2];
    const float* Wq   = (const float*)d_in[3];
    const float* Wke  = (const float*)d_in[4];
    const float* Wv   = (const float*)d_in[5];
    const float* Wkr  = (const float*)d_in[6];
    const float* cb   = (const float*)d_in[7];
    const float* pb   = (const float*)d_in[8];
    const float* Wo_w = (const float*)d_in[9];
    const float* Wo_b = (const float*)d_in[10];
    const float* ln_g = (const float*)d_in[11];
    const float* ln_b = (const float*)d_in[12];
    float* out = (float*)d_out;

    const size_t NQ = (size_t)Bc * Hc * Lc * DKc;   // 2,097,152
    const size_t NR = (size_t)Hc * Lc * DKc;        // 1,048,576
    const size_t need = NQ*2*4 + NR*2 + NQ*4*2;     // ~34 MB
    if (ws_size < need) return;

    u16* qcB  = (u16*)d_ws;
    u16* qpB  = qcB + NQ;
    u16* kB   = qpB + NQ;
    u16* vtB  = kB  + NQ;
    u16* qrtB = vtB + NQ;
    float* Oh = (float*)(qrtB + NR);
    float* yr = Oh + NQ;

    dim3 blk(256);
    // qc = E@Wq + cb ; qp = E@Wq + pb  (bf16 scatter B,H,L,DK)
    gemm_mfma<0,0,1,1,1,0><<<dim3(64,8), blk, 0, stream>>>(E, Wq, cb, pb, nullptr, qcB, qpB, 512);
    // k = E@Wke (bf16 B,H,L,DK)
    gemm_mfma<0,0,1,0,0,0><<<dim3(64,8), blk, 0, stream>>>(E, Wke, nullptr, nullptr, nullptr, kB, nullptr, 512);
    // V^T = Wv^T @ Ev^T (bf16 B,H,DK,L): A = Wv (AT), "W" = Ev (WT rows = ii)
    gemm_mfma<1,1,2,0,0,0><<<dim3(8,64), blk, 0, stream>>>(Wv, Ev, nullptr, nullptr, nullptr, vtB, nullptr, 512);
    // QRT[h][m][dk] = (Wkr@R)[h*64+dk][m]: A = R (AT, ldA=2048), W = Wkr (WT)
    gemm_mfma<1,1,3,0,0,0><<<dim3(32,8), blk, 0, stream>>>(R, Wkr, nullptr, nullptr, nullptr, qrtB, nullptr, 2048);
    // fused MFMA attention
    attn_mfma<<<dim3(512), blk, 0, stream>>>(qcB, qpB, kB, vtB, qrtB, Oh);
    // y = Ev + Oh(flat 4096x512) @ Wo_w^T + Wo_b (fp32)
    gemm_mfma<0,1,0,0,1,1><<<dim3(64,8), blk, 0, stream>>>(Oh, Wo_w, Wo_b, nullptr, Ev, yr, nullptr, 512);
    // layernorm
    ln_kernel<<<dim3(4096), blk, 0, stream>>>(yr, ln_g, ln_b, out);
}

// Round 6
// 203.374 us; speedup vs baseline: 17.4147x; 1.3636x over previous
//
#include <hip/hip_runtime.h>
#include <hip/hip_bf16.h>

// Problem constants
#define Lc   2048
#define Dc   512
#define Hc   8
#define DKc  64
#define Bc   2
#define NSPLIT 4
#define BHLc (Bc*Hc*Lc)

typedef __attribute__((ext_vector_type(8))) short bf16x8;
typedef __attribute__((ext_vector_type(4))) float f32x4;
typedef __attribute__((ext_vector_type(4))) int   i32x4;
typedef unsigned short u16;

#define MFMA16(a, b, c) __builtin_amdgcn_mfma_f32_16x16x32_bf16((a), (b), (c), 0, 0, 0)

__device__ __forceinline__ u16 f2bf(float x) {
    union { float f; unsigned u; } v; v.f = x;
    unsigned r = v.u + 0x7FFFu + ((v.u >> 16) & 1u);   // RNE
    return (u16)(r >> 16);
}

union U16x8 { u16 us[8]; i32x4 v; };

// ---------------------------------------------------------------------------
// Stage a 64x64 fp32 tile -> bf16 LDS [row][k], XOR-swizzled 16B groups
// (slot g ^= row&7). TRANS=0: sDst[row][k] = src[(r0+row)*ld + k0+k]
//                    TRANS=1: sDst[row][k] = src[(k0+k)*ld + r0+row]
// ---------------------------------------------------------------------------
template<int TRANS>
__device__ __forceinline__ void stage_tile(u16* sDst, const float* __restrict__ src,
                                           int r0, int k0, int ld, int t)
{
    if (!TRANS) {
        const int row = t >> 2, q = t & 3;
        const float* s = src + (size_t)(r0 + row) * ld + k0 + q * 16;
        float4 f0 = ((const float4*)s)[0];
        float4 f1 = ((const float4*)s)[1];
        float4 f2 = ((const float4*)s)[2];
        float4 f3 = ((const float4*)s)[3];
        U16x8 a, b;
        a.us[0]=f2bf(f0.x); a.us[1]=f2bf(f0.y); a.us[2]=f2bf(f0.z); a.us[3]=f2bf(f0.w);
        a.us[4]=f2bf(f1.x); a.us[5]=f2bf(f1.y); a.us[6]=f2bf(f1.z); a.us[7]=f2bf(f1.w);
        b.us[0]=f2bf(f2.x); b.us[1]=f2bf(f2.y); b.us[2]=f2bf(f2.z); b.us[3]=f2bf(f2.w);
        b.us[4]=f2bf(f3.x); b.us[5]=f2bf(f3.y); b.us[6]=f2bf(f3.z); b.us[7]=f2bf(f3.w);
        const int r7 = row & 7, base = row * 64;
        *(i32x4*)&sDst[base + (((q*2)     ^ r7) << 3)] = a.v;
        *(i32x4*)&sDst[base + (((q*2 + 1) ^ r7) << 3)] = b.v;
    } else {
        const int qq = t & 31, mg = t >> 5;      // k-pair 2*qq, row-chunk mg*8
        const float* s0 = src + (size_t)(k0 + 2*qq) * ld + r0 + mg*8;
        const float* s1 = s0 + ld;
        float4 x0 = ((const float4*)s0)[0], x1 = ((const float4*)s0)[1];
        float4 y0 = ((const float4*)s1)[0], y1 = ((const float4*)s1)[1];
        float e0[8] = {x0.x,x0.y,x0.z,x0.w,x1.x,x1.y,x1.z,x1.w};
        float e1[8] = {y0.x,y0.y,y0.z,y0.w,y1.x,y1.y,y1.z,y1.w};
        unsigned* d32 = (unsigned*)sDst;
        const int g = qq >> 2, off = qq & 3;
#pragma unroll
        for (int e = 0; e < 8; ++e) {
            const int m = mg*8 + e;
            unsigned pk = (unsigned)f2bf(e0[e]) | ((unsigned)f2bf(e1[e]) << 16);
            d32[m*32 + ((g ^ (m & 7)) << 2) + off] = pk;
        }
    }
}

// ---------------------------------------------------------------------------
// MFMA GEMM: C[M x N] = A'[M x 512] @ W'[512 x N], bf16 inputs (converted in
// staging), f32 accum. 64x64 block tile, 4 waves (2x2), wave tile 32x32.
// OUTMODE: 0 fp32 row-major (+bias/add), 1 bf16 scatter (B,H,L,DK) (+DUAL),
//          2 bf16 scatter V^T (B,H,DK,L), 3 bf16 QRT [h][m][dk]
// ---------------------------------------------------------------------------
template<int AT, int WT, int OUTMODE, int DUAL, int HASBIAS, int ADDSRC>
__global__ __launch_bounds__(256)
void gemm_mfma(const float* __restrict__ A, const float* __restrict__ W,
               const float* __restrict__ b1, const float* __restrict__ b2,
               const float* __restrict__ add, void* __restrict__ o1v,
               void* __restrict__ o2v, int ldA)
{
    __shared__ __align__(16) u16 sA[64*64];
    __shared__ __align__(16) u16 sB[64*64];
    const int m0 = blockIdx.x * 64, n0 = blockIdx.y * 64;
    const int t = threadIdx.x, lane = t & 63, w = t >> 6;
    const int l15 = lane & 15, lg = lane >> 4;
    const int wm = w >> 1, wn = w & 1;

    f32x4 acc[2][2] = {};

    for (int k0 = 0; k0 < 512; k0 += 64) {
        __syncthreads();
        stage_tile<AT>(sA, A, m0, k0, AT ? ldA : 512, t);
        stage_tile<WT ? 0 : 1>(sB, W, n0, k0, 512, t);
        __syncthreads();
        const int l7 = l15 & 7;
#pragma unroll
        for (int kh = 0; kh < 2; ++kh) {
            bf16x8 av[2], bv[2];
#pragma unroll
            for (int f = 0; f < 2; ++f) {
                const int ra = wm*32 + f*16 + l15;
                av[f] = *(const bf16x8*)&sA[ra*64 + (((kh*4 + lg) ^ l7) << 3)];
                const int rb = wn*32 + f*16 + l15;
                bv[f] = *(const bf16x8*)&sB[rb*64 + (((kh*4 + lg) ^ l7) << 3)];
            }
#pragma unroll
            for (int fm = 0; fm < 2; ++fm)
#pragma unroll
                for (int fn = 0; fn < 2; ++fn)
                    acc[fm][fn] = MFMA16(av[fm], bv[fn], acc[fm][fn]);
        }
    }

#pragma unroll
    for (int fm = 0; fm < 2; ++fm)
#pragma unroll
    for (int fn = 0; fn < 2; ++fn) {
        const int colg = n0 + wn*32 + fn*16 + l15;
#pragma unroll
        for (int r = 0; r < 4; ++r) {
            const int row = m0 + wm*32 + fm*16 + lg*4 + r;
            float v = acc[fm][fn][r];
            if (OUTMODE == 0) {
                if (HASBIAS) v += b1[colg];
                if (ADDSRC)  v += add[(size_t)row*512 + colg];
                ((float*)o1v)[(size_t)row*512 + colg] = v;
            } else if (OUTMODE == 1) {
                if (HASBIAS) v += b1[colg];
                const int h = colg >> 6, dk = colg & 63;
                const int bb = row >> 11, ii = row & 2047;
                const size_t idx = (((size_t)(bb*Hc + h)*Lc + ii) << 6) + dk;
                ((u16*)o1v)[idx] = f2bf(v);
                if (DUAL)
                    ((u16*)o2v)[idx] = f2bf(acc[fm][fn][r] + b2[colg]);
            } else if (OUTMODE == 2) {
                const int h = row >> 6, dk = row & 63;
                const int bb = colg >> 11, ii = colg & 2047;
                ((u16*)o1v)[((size_t)(bb*Hc + h)*DKc + dk)*Lc + ii] = f2bf(v);
            } else {
                const int h = colg >> 6, dk = colg & 63;
                ((u16*)o1v)[(((size_t)h*Lc + row) << 6) + dk] = f2bf(v);
            }
        }
    }
}

// ---------------------------------------------------------------------------
// MFMA fused relative attention, j-split flash style.
// Grid 2048 = (b, h, split, i-tile) XCD-swizzled; each block does 8 j-tiles
// of its split and writes raw O + (m, l) partials. LDS 50 KB -> 3 blk/CU.
// ---------------------------------------------------------------------------
__global__ __launch_bounds__(256)
void attn_mfma(const u16* __restrict__ qc, const u16* __restrict__ qp,
               const u16* __restrict__ kk, const u16* __restrict__ vt,
               const u16* __restrict__ qrt, float* __restrict__ Opart,
               float* __restrict__ mlbuf)
{
    __shared__ __align__(16) u16 sK[64*64];
    __shared__ __align__(16) u16 sVT[64*64];
    __shared__ __align__(16) u16 sBand[128*64];
    __shared__ __align__(16) char sPU[4*4608];  // per-wave: f32[16][68] P2 U u16[16][64] P

    // XCD swizzle: nwg=2048 (%8==0) -> orig = (bx&7)*256 + bx>>3  (bijective)
    const int orig = ((blockIdx.x & 7) << 8) | (blockIdx.x >> 3);
    const int it = orig & 31;
    const int sp = (orig >> 5) & (NSPLIT - 1);
    const int bh = orig >> 7;
    const int h = bh & 7, b = bh >> 3;
    const int i0 = it << 6;
    const int t = threadIdx.x;
    const int lane = t & 63, w = t >> 6;
    const int l15 = lane & 15, lg = lane >> 4;

    float* p2w = (float*)(sPU + (size_t)w * 4608);
    u16*   spw = (u16*)(sPU + (size_t)w * 4608);

    const size_t ho = (size_t)(b*Hc + h) * (Lc * DKc);
    const u16* qcH  = qc  + ho;
    const u16* qpH  = qp  + ho;
    const u16* kH   = kk  + ho;
    const u16* vtH  = vt  + ho;
    const u16* qrtH = qrt + (size_t)h * (Lc * DKc);

    // Q fragments in registers
    const int rowA = i0 + w*16 + l15;
    const int rowB = (rowA + 1 < Lc) ? rowA + 1 : Lc - 1;
    bf16x8 qc0 = *(const bf16x8*)(qcH + (size_t)rowA*64 +      lg*8);
    bf16x8 qc1 = *(const bf16x8*)(qcH + (size_t)rowA*64 + 32 + lg*8);
    bf16x8 qa0 = *(const bf16x8*)(qpH + (size_t)rowA*64 +      lg*8);
    bf16x8 qa1 = *(const bf16x8*)(qpH + (size_t)rowA*64 + 32 + lg*8);
    bf16x8 qb0 = *(const bf16x8*)(qpH + (size_t)rowB*64 +      lg*8);
    bf16x8 qb1 = *(const bf16x8*)(qpH + (size_t)rowB*64 + 32 + lg*8);

    f32x4 oacc[4] = {};
    float mrow[4] = {-1e30f, -1e30f, -1e30f, -1e30f};
    float lrow[4] = {0.f, 0.f, 0.f, 0.f};

    for (int jq = 0; jq < 32/NSPLIT; ++jq) {
        const int jt = sp * (32/NSPLIT) + jq;
        const int j0 = jt << 6;
        const int dBase = j0 - i0 - 63;
        __syncthreads();
        // ---- stage K, VT, Band (direct global -> LDS) ----
#pragma unroll
        for (int p = 0; p < 2; ++p) {
            const int s = t + p*256, row = s >> 3, g = s & 7;
            const int sl = row*64 + ((g ^ (row & 7)) << 3);
            *(i32x4*)&sK[sl]  = *(const i32x4*)(kH  + (size_t)(j0+row)*64 + g*8);
            *(i32x4*)&sVT[sl] = *(const i32x4*)(vtH + (size_t)row*Lc + j0 + g*8);
        }
#pragma unroll
        for (int p = 0; p < 4; ++p) {
            const int s = t + p*256, dd = s >> 3, g = s & 7;
            const int d = dBase + dd;
            const int m = (d <= 0) ? (d + Lc - 1) : ((d >= 2) ? (d - 2) : 0);
            *(i32x4*)&sBand[dd*64 + ((g ^ (dd & 7)) << 3)] =
                *(const i32x4*)(qrtH + (size_t)m*64 + g*8);
        }
        __syncthreads();

        // ---- qk scores ----
        f32x4 sc[4];
#pragma unroll
        for (int nb = 0; nb < 4; ++nb) {
            const int row = nb*16 + l15;
            bf16x8 k0 = *(const bf16x8*)&sK[row*64 + ((( lg    ) ^ (row & 7)) << 3)];
            bf16x8 k1 = *(const bf16x8*)&sK[row*64 + (((lg + 4) ^ (row & 7)) << 3)];
            f32x4 z = {0.f, 0.f, 0.f, 0.f};
            z = MFMA16(qc0, k0, z);
            z = MFMA16(qc1, k1, z);
            sc[nb] = z;
        }

        // ---- P2 band GEMM -> compact per-wave LDS (slot c == jl) ----
#pragma unroll
        for (int cb = 0; cb < 8; ++cb) {
            const int row = cb*16 + l15;
            bf16x8 b0 = *(const bf16x8*)&sBand[row*64 + ((( lg    ) ^ (row & 7)) << 3)];
            bf16x8 b1 = *(const bf16x8*)&sBand[row*64 + (((lg + 4) ^ (row & 7)) << 3)];
            f32x4 z = {0.f, 0.f, 0.f, 0.f};
            if ((dBase + cb*16) >= 1) {
                z = MFMA16(qb0, b0, z);
                z = MFMA16(qb1, b1, z);
            } else {
                z = MFMA16(qa0, b0, z);
                z = MFMA16(qa1, b1, z);
            }
#pragma unroll
            for (int r = 0; r < 4; ++r) {
                const int blm = lg*4 + r;
                const int c = cb*16 + l15 + (w*16 + blm) - 63;
                if (c >= 0 && c < 64) p2w[blm*68 + c] = z[r];
            }
        }
        __asm__ volatile("" ::: "memory");

        // ---- gather shift term + online softmax ----
        float fsc[4];
#pragma unroll
        for (int r = 0; r < 4; ++r) {
            const int blm = lg*4 + r;
            const int blg = w*16 + blm;
#pragma unroll
            for (int nb = 0; nb < 4; ++nb) {
                const int jl = nb*16 + l15;
                const int d  = dBase + jl - blg + 63;
                const float pv = p2w[blm*68 + jl];
                sc[nb][r] += (d == 1) ? 0.f : pv;
            }
            float mx = fmaxf(fmaxf(sc[0][r], sc[1][r]), fmaxf(sc[2][r], sc[3][r]));
            mx = fmaxf(mx, __shfl_xor(mx, 1, 64));
            mx = fmaxf(mx, __shfl_xor(mx, 2, 64));
            mx = fmaxf(mx, __shfl_xor(mx, 4, 64));
            mx = fmaxf(mx, __shfl_xor(mx, 8, 64));
            const float mnew = fmaxf(mrow[r], mx);
            const float fac  = __expf(mrow[r] - mnew);
            mrow[r] = mnew;
            float p0 = __expf(sc[0][r] - mnew);
            float p1 = __expf(sc[1][r] - mnew);
            float p2 = __expf(sc[2][r] - mnew);
            float p3 = __expf(sc[3][r] - mnew);
            sc[0][r] = p0; sc[1][r] = p1; sc[2][r] = p2; sc[3][r] = p3;
            float ps = p0 + p1 + p2 + p3;
            ps += __shfl_xor(ps, 1, 64);
            ps += __shfl_xor(ps, 2, 64);
            ps += __shfl_xor(ps, 4, 64);
            ps += __shfl_xor(ps, 8, 64);
            lrow[r] = lrow[r] * fac + ps;
            fsc[r] = fac;
        }
#pragma unroll
        for (int nb = 0; nb < 4; ++nb)
#pragma unroll
            for (int r = 0; r < 4; ++r)
                oacc[nb][r] *= fsc[r];
        __asm__ volatile("" ::: "memory");

        // ---- write P (bf16, swizzled; overwrites P2 region; wave-private) ----
#pragma unroll
        for (int r = 0; r < 4; ++r) {
            const int blm = lg*4 + r;
#pragma unroll
            for (int nb = 0; nb < 4; ++nb) {
                const int jl = nb*16 + l15;
                spw[blm*64 + (((jl >> 3) ^ (blm & 7)) << 3) + (jl & 7)] = f2bf(sc[nb][r]);
            }
        }
        __asm__ volatile("" ::: "memory");

        // ---- PV ----
        {
            bf16x8 pa0 = *(const bf16x8*)&spw[l15*64 + ((( lg    ) ^ (l15 & 7)) << 3)];
            bf16x8 pa1 = *(const bf16x8*)&spw[l15*64 + (((lg + 4) ^ (l15 & 7)) << 3)];
#pragma unroll
            for (int nb = 0; nb < 4; ++nb) {
                const int row = nb*16 + l15;
                bf16x8 v0 = *(const bf16x8*)&sVT[row*64 + ((( lg    ) ^ (row & 7)) << 3)];
                bf16x8 v1 = *(const bf16x8*)&sVT[row*64 + (((lg + 4) ^ (row & 7)) << 3)];
                oacc[nb] = MFMA16(pa0, v0, oacc[nb]);
                oacc[nb] = MFMA16(pa1, v1, oacc[nb]);
            }
        }
    }

    // ---- epilogue: store raw O partial + (m,l) ----
    float* Op = Opart + (size_t)sp * (Bc*Hc*Lc*DKc) + ho;
#pragma unroll
    for (int r = 0; r < 4; ++r) {
        const int bl = w*16 + lg*4 + r;
#pragma unroll
        for (int nb = 0; nb < 4; ++nb)
            Op[(size_t)(i0 + bl)*64 + nb*16 + l15] = oacc[nb][r];
        if (l15 == 0) {
            const int rglob = (b*Hc + h)*Lc + i0 + bl;
            *(float2*)&mlbuf[((size_t)sp*BHLc + rglob)*2] = make_float2(mrow[r], lrow[r]);
        }
    }
}

// ---------------------------------------------------------------------------
// Combine NSPLIT partials: O = sum_s Op_s * e^(m_s - M) / sum_s l_s e^(m_s-M).
// In-place into split 0 (each thread reads its slots before writing).
// ---------------------------------------------------------------------------
__global__ __launch_bounds__(256)
void attn_combine(const float* __restrict__ Opart, const float* __restrict__ mlbuf,
                  float* __restrict__ Oh)
{
    const int t = threadIdx.x;
    const int row = blockIdx.x * 64 + (t >> 2);
    const int q = t & 3;
    const size_t NQl = (size_t)Bc * Hc * Lc * DKc;

    float m[NSPLIT], l[NSPLIT];
#pragma unroll
    for (int s = 0; s < NSPLIT; ++s) {
        float2 ml = *(const float2*)&mlbuf[((size_t)s*BHLc + row)*2];
        m[s] = ml.x; l[s] = ml.y;
    }
    float M = fmaxf(fmaxf(m[0], m[1]), fmaxf(m[2], m[3]));
    float wgt[NSPLIT], wsum = 0.f;
#pragma unroll
    for (int s = 0; s < NSPLIT; ++s) { wgt[s] = __expf(m[s] - M); wsum += l[s]*wgt[s]; }
    const float inv = 1.f / wsum;

    f32x4 acc[4] = {};
#pragma unroll
    for (int s = 0; s < NSPLIT; ++s) {
        const f32x4* src = (const f32x4*)(Opart + (size_t)s*NQl + (size_t)row*64 + q*16);
#pragma unroll
        for (int u = 0; u < 4; ++u)
            acc[u] += src[u] * wgt[s];
    }
    f32x4* dst = (f32x4*)(Oh + (size_t)row*64 + q*16);
#pragma unroll
    for (int u = 0; u < 4; ++u)
        dst[u] = acc[u] * inv;
}

// ---------------------------------------------------------------------------
// LayerNorm over D=512 per row (4096 rows).
// ---------------------------------------------------------------------------
__global__ __launch_bounds__(256)
void ln_kernel(const float* __restrict__ yr, const float* __restrict__ g,
               const float* __restrict__ be, float* __restrict__ out)
{
    const int row = blockIdx.x;
    const int t   = threadIdx.x;
    const float2 v = *(const float2*)&yr[(size_t)row * 512 + t*2];
    float sum = v.x + v.y;
    float sq  = v.x*v.x + v.y*v.y;
#pragma unroll
    for (int off = 1; off < 64; off <<= 1) {
        sum += __shfl_xor(sum, off, 64);
        sq  += __shfl_xor(sq,  off, 64);
    }
    __shared__ float ssum[4], ssq[4];
    if ((t & 63) == 0) { ssum[t >> 6] = sum; ssq[t >> 6] = sq; }
    __syncthreads();
    sum = ssum[0] + ssum[1] + ssum[2] + ssum[3];
    sq  = ssq[0]  + ssq[1]  + ssq[2]  + ssq[3];
    const float mu   = sum * (1.f / 512.f);
    const float var  = sq * (1.f / 512.f) - mu * mu;
    const float rstd = rsqrtf(var + 1e-5f);
    float2 ov;
    ov.x = (v.x - mu) * rstd * g[t*2+0] + be[t*2+0];
    ov.y = (v.y - mu) * rstd * g[t*2+1] + be[t*2+1];
    *(float2*)&out[(size_t)row * 512 + t*2] = ov;
}

// ---------------------------------------------------------------------------
extern "C" void kernel_launch(void* const* d_in, const int* in_sizes, int n_in,
                              void* d_out, int out_size, void* d_ws, size_t ws_size,
                              hipStream_t stream)
{
    const float* E    = (const float*)d_in[0];
    const float* Ev   = (const float*)d_in[1];
    const float* R    = (const float*)d_in[2];
    const float* Wq   = (const float*)d_in[3];
    const float* Wke  = (const float*)d_in[4];
    const float* Wv   = (const float*)d_in[5];
    const float* Wkr  = (const float*)d_in[6];
    const float* cb   = (const float*)d_in[7];
    const float* pb   = (const float*)d_in[8];
    const float* Wo_w = (const float*)d_in[9];
    const float* Wo_b = (const float*)d_in[10];
    const float* ln_g = (const float*)d_in[11];
    const float* ln_b = (const float*)d_in[12];
    float* out = (float*)d_out;

    const size_t NQ = (size_t)Bc * Hc * Lc * DKc;   // 2,097,152
    const size_t NR = (size_t)Hc * Lc * DKc;        // 1,048,576
    const size_t need = (4*NQ + NR)*2 + (size_t)NSPLIT*NQ*4 + (size_t)NSPLIT*BHLc*2*4;
    if (ws_size < need) return;

    u16* qcB  = (u16*)d_ws;
    u16* qpB  = qcB + NQ;
    u16* kB   = qpB + NQ;
    u16* vtB  = kB  + NQ;
    u16* qrtB = vtB + NQ;
    float* Opart = (float*)(qrtB + NR);        // NSPLIT * NQ floats
    float* mlbuf = Opart + (size_t)NSPLIT*NQ;  // NSPLIT * BHL * 2 floats
    float* Oh = Opart;                          // combine output aliases split 0
    float* yr = Opart + NQ;                     // aliases split 1 (free after combine)

    dim3 blk(256);
    // qc = E@Wq + cb ; qp = E@Wq + pb  (bf16 scatter B,H,L,DK)
    gemm_mfma<0,0,1,1,1,0><<<dim3(64,8), blk, 0, stream>>>(E, Wq, cb, pb, nullptr, qcB, qpB, 512);
    // k = E@Wke (bf16 B,H,L,DK)
    gemm_mfma<0,0,1,0,0,0><<<dim3(64,8), blk, 0, stream>>>(E, Wke, nullptr, nullptr, nullptr, kB, nullptr, 512);
    // V^T = Wv^T @ Ev^T (bf16 B,H,DK,L)
    gemm_mfma<1,1,2,0,0,0><<<dim3(8,64), blk, 0, stream>>>(Wv, Ev, nullptr, nullptr, nullptr, vtB, nullptr, 512);
    // QRT[h][m][dk] = (Wkr@R)[h*64+dk][m]
    gemm_mfma<1,1,3,0,0,0><<<dim3(32,8), blk, 0, stream>>>(R, Wkr, nullptr, nullptr, nullptr, qrtB, nullptr, 2048);
    // fused MFMA attention, j-split: grid = B*H*NSPLIT*32 = 2048
    attn_mfma<<<dim3(Bc*Hc*NSPLIT*32), blk, 0, stream>>>(qcB, qpB, kB, vtB, qrtB, Opart, mlbuf);
    attn_combine<<<dim3(BHLc/64), blk, 0, stream>>>(Opart, mlbuf, Oh);
    // y = Ev + Oh(flat 4096x512) @ Wo_w^T + Wo_b (fp32)
    gemm_mfma<0,1,0,0,1,1><<<dim3(64,8), blk, 0, stream>>>(Oh, Wo_w, Wo_b, nullptr, Ev, yr, nullptr, 512);
    // layernorm
    ln_kernel<<<dim3(4096), blk, 0, stream>>>(yr, ln_g, ln_b, out);
}